// Round 1
// baseline (40.222 us; speedup 1.0000x reference)
//
#include <hip/hip_runtime.h>

// out[b,o] = min_i max(x[b,i], w[i,o])
// (hard - stop_gradient(smooth) + smooth == hard in forward, to ~1 ulp)
//
// B=512, I=512, O=1024, all fp32.

#define B_DIM 512
#define I_DIM 512
#define O_DIM 1024

#define BM 32
#define BN 64
#define KI 32
#define NCHUNK (I_DIM / KI)

__global__ __launch_bounds__(256, 1) void SmoothSTEMinMax_kernel(
    const float* __restrict__ x,     // [B, I]
    const float* __restrict__ w,     // [I, O]
    float* __restrict__ out) {       // [B, O]
  __shared__ float xs[KI][BM + 1];   // xs[ki][row], padded: conflict-free
  __shared__ float ws[KI][BN];       // ws[ki][col]

  const int tid = threadIdx.x;
  const int tx = tid & 15;   // col group: 4 cols each
  const int ty = tid >> 4;   // row group: 2 rows each
  const int b0 = blockIdx.x * BM;
  const int o0 = blockIdx.y * BN;

  // staging thread mapping
  const int xr = tid >> 5;         // x row base (0..7), +8 per pass
  const int xk = tid & 31;         // x ki (coalesced along I)
  const int wk = tid >> 4;         // w ki base (0..15), +16 for second pass
  const int wc = (tid & 15) * 4;   // w col (float4, coalesced along O)

  float xreg[4];
  float4 wreg[2];

  // prologue: prefetch chunk 0 into registers
#pragma unroll
  for (int p = 0; p < 4; ++p)
    xreg[p] = x[(b0 + xr + 8 * p) * I_DIM + xk];
#pragma unroll
  for (int p = 0; p < 2; ++p)
    wreg[p] = *reinterpret_cast<const float4*>(&w[(wk + 16 * p) * O_DIM + o0 + wc]);

  float acc[2][4];
#pragma unroll
  for (int r = 0; r < 2; ++r)
#pragma unroll
    for (int c = 0; c < 4; ++c) acc[r][c] = 3.402823466e+38f;

  for (int ch = 0; ch < NCHUNK; ++ch) {
    // write staged registers to LDS
#pragma unroll
    for (int p = 0; p < 4; ++p) xs[xk][xr + 8 * p] = xreg[p];
#pragma unroll
    for (int p = 0; p < 2; ++p)
      *reinterpret_cast<float4*>(&ws[wk + 16 * p][wc]) = wreg[p];
    __syncthreads();

    // issue next chunk's global loads (land before next iteration's LDS write)
    if (ch + 1 < NCHUNK) {
      const int i0 = (ch + 1) * KI;
#pragma unroll
      for (int p = 0; p < 4; ++p)
        xreg[p] = x[(b0 + xr + 8 * p) * I_DIM + i0 + xk];
#pragma unroll
      for (int p = 0; p < 2; ++p)
        wreg[p] = *reinterpret_cast<const float4*>(&w[(i0 + wk + 16 * p) * O_DIM + o0 + wc]);
    }

    // min-max inner loop over this K chunk
#pragma unroll
    for (int ki = 0; ki < KI; ++ki) {
      const float xv0 = xs[ki][ty * 2 + 0];
      const float xv1 = xs[ki][ty * 2 + 1];
      const float4 wv = *reinterpret_cast<const float4*>(&ws[ki][tx * 4]);
      acc[0][0] = fminf(acc[0][0], fmaxf(xv0, wv.x));
      acc[0][1] = fminf(acc[0][1], fmaxf(xv0, wv.y));
      acc[0][2] = fminf(acc[0][2], fmaxf(xv0, wv.z));
      acc[0][3] = fminf(acc[0][3], fmaxf(xv0, wv.w));
      acc[1][0] = fminf(acc[1][0], fmaxf(xv1, wv.x));
      acc[1][1] = fminf(acc[1][1], fmaxf(xv1, wv.y));
      acc[1][2] = fminf(acc[1][2], fmaxf(xv1, wv.z));
      acc[1][3] = fminf(acc[1][3], fmaxf(xv1, wv.w));
    }
    __syncthreads();
  }

  // epilogue: coalesced float4 stores
#pragma unroll
  for (int r = 0; r < 2; ++r) {
    const float4 v = make_float4(acc[r][0], acc[r][1], acc[r][2], acc[r][3]);
    *reinterpret_cast<float4*>(&out[(b0 + ty * 2 + r) * O_DIM + o0 + tx * 4]) = v;
  }
}

extern "C" void kernel_launch(void* const* d_in, const int* in_sizes, int n_in,
                              void* d_out, int out_size, void* d_ws, size_t ws_size,
                              hipStream_t stream) {
  const float* x = (const float*)d_in[0];   // [512, 512]
  const float* w = (const float*)d_in[1];   // [512, 1024]
  float* out = (float*)d_out;               // [512, 1024]

  dim3 grid(B_DIM / BM, O_DIM / BN);        // 16 x 16 = 256 blocks
  SmoothSTEMinMax_kernel<<<grid, 256, 0, stream>>>(x, w, out);
}